// Round 1
// baseline (22776.849 us; speedup 1.0000x reference)
//
#include <hip/hip_runtime.h>
#include <hip/hip_bf16.h>
#include <cstdint>
#include <cstddef>

#define Bdim 256
#define Tdim 256
#define Idim 512
#define Hdim 1024
#define Odim 5

using short8 = __attribute__((ext_vector_type(8))) short;
using f32x4  = __attribute__((ext_vector_type(4))) float;

__device__ __forceinline__ short bf16_of(float f) {
  unsigned u = __builtin_bit_cast(unsigned, f);
  u += 0x7fffu + ((u >> 16) & 1u);
  return (short)(u >> 16);
}

__device__ __forceinline__ float sigmf(float x) {
  return 1.0f / (1.0f + __expf(-x));
}

__global__ __launch_bounds__(256) void k_cvt_bf16(const float* __restrict__ src,
                                                  short* __restrict__ dst, int n) {
  int i0 = (blockIdx.x * 256 + threadIdx.x) * 8;
  int stride = gridDim.x * 256 * 8;
  for (int i = i0; i < n; i += stride) {
    float4 u = *reinterpret_cast<const float4*>(src + i);
    float4 v = *reinterpret_cast<const float4*>(src + i + 4);
    short8 o = {bf16_of(u.x), bf16_of(u.y), bf16_of(u.z), bf16_of(u.w),
                bf16_of(v.x), bf16_of(v.y), bf16_of(v.z), bf16_of(v.w)};
    *reinterpret_cast<short8*>(dst + i) = o;
  }
}

__global__ __launch_bounds__(256) void k_init(const float* __restrict__ hidden,
    float* __restrict__ h0f, float* __restrict__ c0f,
    float* __restrict__ h1f, float* __restrict__ c1f,
    short* __restrict__ h0b, short* __restrict__ h1b) {
  const int BH = Bdim * Hdim;
  int i = blockIdx.x * 256 + threadIdx.x;
  if (i < BH) {
    float h0 = hidden[i],        c0 = hidden[BH + i];
    float h1 = hidden[2*BH + i], c1 = hidden[3*BH + i];
    h0f[i] = h0; c0f[i] = c0; h1f[i] = h1; c1f[i] = c1;
    h0b[i] = bf16_of(h0); h1b[i] = bf16_of(h1);
  }
}

// One LSTM cell step for one layer.
// grid: (H/16, B/32); block: 256 threads = 4 waves; wave g handles gate g.
// gates[g][b][h] = sum_k combined[b,k] * W[g*H+h, k] + bias[g,h]
// combined = [h_prev (H) | x_part (K-H)]
template<int LAYER>
__global__ __launch_bounds__(256) void k_cell(
    const short* __restrict__ Wb,    // [4H, K] bf16
    const float* __restrict__ bias,  // [4, H] f32
    const short* __restrict__ hprev, // [B, H] bf16 (this layer's h at t)
    const float* __restrict__ xf,    // layer0: x fp32 [B, T, I]
    const short* __restrict__ xb,    // layer1: layer0 h at t, bf16 [B, H]
    float* __restrict__ cf,          // [B, H] f32, in/out
    float* __restrict__ hf,          // [B, H] f32, out
    short* __restrict__ hb_out,      // [B, H] bf16, out (double buffer)
    int t) {
  constexpr int K = (LAYER == 0) ? (Hdim + Idim) : (2 * Hdim);
  const int h0  = blockIdx.x * 16;
  const int b0  = blockIdx.y * 32;
  const int tid = threadIdx.x;
  const int lane = tid & 63;
  const int g    = tid >> 6;       // wave id = gate index (f,i,g,o)
  const int lr   = lane & 15;
  const int kl   = (lane >> 4) * 8;

  f32x4 acc0 = {0.f, 0.f, 0.f, 0.f};
  f32x4 acc1 = {0.f, 0.f, 0.f, 0.f};
  const short* wrow = Wb + (size_t)(g * Hdim + h0 + lr) * K;
  const short* ha = hprev + (b0 + lr) * Hdim;
  const short* hc = hprev + (b0 + 16 + lr) * Hdim;

  // K-part 1: h_prev (k in [0, H))
  #pragma unroll 4
  for (int k0 = 0; k0 < Hdim; k0 += 32) {
    int k = k0 + kl;
    short8 bfr = *reinterpret_cast<const short8*>(wrow + k);
    short8 a0  = *reinterpret_cast<const short8*>(ha + k);
    short8 a1  = *reinterpret_cast<const short8*>(hc + k);
    acc0 = __builtin_amdgcn_mfma_f32_16x16x32_bf16(a0, bfr, acc0, 0, 0, 0);
    acc1 = __builtin_amdgcn_mfma_f32_16x16x32_bf16(a1, bfr, acc1, 0, 0, 0);
  }
  // K-part 2: x part (k in [H, K))
  if constexpr (LAYER == 0) {
    const float* xa = xf + ((size_t)(b0 + lr) * Tdim + t) * Idim - Hdim;
    const float* xc = xf + ((size_t)(b0 + 16 + lr) * Tdim + t) * Idim - Hdim;
    #pragma unroll 4
    for (int k0 = Hdim; k0 < K; k0 += 32) {
      int k = k0 + kl;
      short8 bfr = *reinterpret_cast<const short8*>(wrow + k);
      float4 u = *reinterpret_cast<const float4*>(xa + k);
      float4 v = *reinterpret_cast<const float4*>(xa + k + 4);
      short8 a0 = {bf16_of(u.x), bf16_of(u.y), bf16_of(u.z), bf16_of(u.w),
                   bf16_of(v.x), bf16_of(v.y), bf16_of(v.z), bf16_of(v.w)};
      u = *reinterpret_cast<const float4*>(xc + k);
      v = *reinterpret_cast<const float4*>(xc + k + 4);
      short8 a1 = {bf16_of(u.x), bf16_of(u.y), bf16_of(u.z), bf16_of(u.w),
                   bf16_of(v.x), bf16_of(v.y), bf16_of(v.z), bf16_of(v.w)};
      acc0 = __builtin_amdgcn_mfma_f32_16x16x32_bf16(a0, bfr, acc0, 0, 0, 0);
      acc1 = __builtin_amdgcn_mfma_f32_16x16x32_bf16(a1, bfr, acc1, 0, 0, 0);
    }
  } else {
    const short* xa = xb + (b0 + lr) * Hdim - Hdim;
    const short* xc = xb + (b0 + 16 + lr) * Hdim - Hdim;
    #pragma unroll 4
    for (int k0 = Hdim; k0 < K; k0 += 32) {
      int k = k0 + kl;
      short8 bfr = *reinterpret_cast<const short8*>(wrow + k);
      short8 a0  = *reinterpret_cast<const short8*>(xa + k);
      short8 a1  = *reinterpret_cast<const short8*>(xc + k);
      acc0 = __builtin_amdgcn_mfma_f32_16x16x32_bf16(a0, bfr, acc0, 0, 0, 0);
      acc1 = __builtin_amdgcn_mfma_f32_16x16x32_bf16(a1, bfr, acc1, 0, 0, 0);
    }
  }

  // stage gates in LDS: [gate][32 local b][16 local h]
  __shared__ float lds[4][32][16];
  float bv = bias[g * Hdim + h0 + lr];  // D col = lane&15 -> h col
  #pragma unroll
  for (int j = 0; j < 4; ++j) {
    int r = (lane >> 4) * 4 + j;       // D row within 16-tile -> batch row
    lds[g][r][lr]      = acc0[j] + bv;
    lds[g][16 + r][lr] = acc1[j] + bv;
  }
  __syncthreads();

  // fused elementwise: c' = f*c + i*g ; h' = o*tanh(c')
  #pragma unroll
  for (int e = tid; e < 32 * 16; e += 256) {
    int lb = e >> 4, lh = e & 15;
    float fg = sigmf(lds[0][lb][lh]);
    float ig = sigmf(lds[1][lb][lh]);
    float gg = tanhf(lds[2][lb][lh]);
    float og = sigmf(lds[3][lb][lh]);
    int idx = (b0 + lb) * Hdim + (h0 + lh);
    float c = cf[idx];
    float cn = fg * c + ig * gg;
    float hn = og * tanhf(cn);
    cf[idx] = cn;
    hf[idx] = hn;
    hb_out[idx] = bf16_of(hn);
  }
}

__global__ __launch_bounds__(256) void k_outproj(const float* __restrict__ h1f,
    const float* __restrict__ Wout, const float* __restrict__ bout,
    float* __restrict__ out) {
  int b = blockIdx.x;
  int tid = threadIdx.x;
  float hv[4];
  #pragma unroll
  for (int j = 0; j < 4; ++j) hv[j] = h1f[b * Hdim + tid + j * 256];
  __shared__ float red[Odim][4];
  #pragma unroll
  for (int o = 0; o < Odim; ++o) {
    float p = 0.f;
    #pragma unroll
    for (int j = 0; j < 4; ++j) p += hv[j] * Wout[o * Hdim + tid + j * 256];
    #pragma unroll
    for (int s = 32; s > 0; s >>= 1) p += __shfl_down(p, s, 64);
    if ((tid & 63) == 0) red[o][tid >> 6] = p;
  }
  __syncthreads();
  if (tid < Odim)
    out[b * Odim + tid] = red[tid][0] + red[tid][1] + red[tid][2] + red[tid][3] + bout[tid];
}

__global__ __launch_bounds__(256) void k_finals(const float* __restrict__ h0f,
    const float* __restrict__ c0f, const float* __restrict__ h1f,
    const float* __restrict__ c1f, float* __restrict__ dst) {
  const int BH = Bdim * Hdim;
  int n = 4 * BH;
  int stride = gridDim.x * 256;
  for (int i = blockIdx.x * 256 + threadIdx.x; i < n; i += stride) {
    int q = i >> 18;              // BH = 2^18
    int r = i & (BH - 1);
    const float* s = (q == 0) ? h0f : (q == 1) ? c0f : (q == 2) ? h1f : c1f;
    dst[i] = s[r];
  }
}

extern "C" void kernel_launch(void* const* d_in, const int* in_sizes, int n_in,
                              void* d_out, int out_size, void* d_ws, size_t ws_size,
                              hipStream_t stream) {
  const float* x      = (const float*)d_in[0];
  const float* hidden = (const float*)d_in[1];
  const float* W0     = (const float*)d_in[2];
  const float* b0     = (const float*)d_in[3];
  const float* W1     = (const float*)d_in[4];
  const float* b1     = (const float*)d_in[5];
  const float* Wout   = (const float*)d_in[6];
  const float* bout   = (const float*)d_in[7];
  float* out = (float*)d_out;

  char* ws = (char*)d_ws;
  size_t off = 0;
  auto alloc = [&](size_t bytes) {
    void* p = ws + off;
    off += (bytes + 255) & ~(size_t)255;
    return p;
  };
  const int BH = Bdim * Hdim;
  short* W0b  = (short*)alloc((size_t)4096 * 1536 * 2);
  short* W1b  = (short*)alloc((size_t)4096 * 2048 * 2);
  float* h0f  = (float*)alloc((size_t)BH * 4);
  float* c0f  = (float*)alloc((size_t)BH * 4);
  float* h1f  = (float*)alloc((size_t)BH * 4);
  float* c1f  = (float*)alloc((size_t)BH * 4);
  short* h0bA = (short*)alloc((size_t)BH * 2);
  short* h0bB = (short*)alloc((size_t)BH * 2);
  short* h1bA = (short*)alloc((size_t)BH * 2);
  short* h1bB = (short*)alloc((size_t)BH * 2);
  short* h0bufs[2] = {h0bA, h0bB};
  short* h1bufs[2] = {h1bA, h1bB};

  k_cvt_bf16<<<2048, 256, 0, stream>>>(W0, W0b, 4096 * 1536);
  k_cvt_bf16<<<2048, 256, 0, stream>>>(W1, W1b, 4096 * 2048);
  k_init<<<BH / 256, 256, 0, stream>>>(hidden, h0f, c0f, h1f, c1f, h0bufs[0], h1bufs[0]);

  for (int t = 0; t < Tdim; ++t) {
    k_cell<0><<<dim3(64, 8), 256, 0, stream>>>(
        W0b, b0, h0bufs[t & 1], x, nullptr,
        c0f, h0f, h0bufs[(t + 1) & 1], t);
    k_cell<1><<<dim3(64, 8), 256, 0, stream>>>(
        W1b, b1, h1bufs[t & 1], nullptr, h0bufs[(t + 1) & 1],
        c1f, h1f, h1bufs[(t + 1) & 1], t);
  }

  k_outproj<<<Bdim, 256, 0, stream>>>(h1f, Wout, bout, out);
  k_finals<<<1024, 256, 0, stream>>>(h0f, c0f, h1f, c1f, out + Bdim * Odim);
}